// Round 11
// baseline (5394.413 us; speedup 1.0000x reference)
//
#include <hip/hip_runtime.h>
#include <cmath>

#define LOG2E 1.44269504088896340736f
#define TMAX 2048

#if __has_builtin(__builtin_amdgcn_exp2f)
#define EXP2F(x) __builtin_amdgcn_exp2f(x)
#else
#define EXP2F(x) exp2f(x)
#endif
#if __has_builtin(__builtin_amdgcn_rcpf)
#define RCPF(x) __builtin_amdgcn_rcpf(x)
#else
#define RCPF(x) (1.0f / (x))
#endif

typedef float float4v __attribute__((ext_vector_type(4)));

__device__ __forceinline__ float fexp(float x)  { return EXP2F(x * LOG2E); }
// tanh(x) = 1 - 2/(1 + e^{2x})
__device__ __forceinline__ float ftanh(float x) { return 1.0f - 2.0f * RCPF(1.0f + EXP2F(x * (2.0f * LOG2E))); }
// _step(x) = (tanh(5x)+1)/2 = sigmoid(10x)
__device__ __forceinline__ float fstep(float x) { return RCPF(1.0f + EXP2F(x * (-10.0f * LOG2E))); }
__device__ __forceinline__ float fsinh(float x) { float e = fexp(x); return 0.5f * (e - RCPF(e)); }

__device__ __forceinline__ int fadd_i(int a, int b) {
    return __builtin_bit_cast(int, __builtin_bit_cast(float, a) + __builtin_bit_cast(float, b));
}

// full-wave (64 lane) sum via DPP tree; TOTAL VALID IN LANE 63 ONLY.
__device__ __forceinline__ float wave_sum63(float x) {
    int v = __builtin_bit_cast(int, x);
    v = fadd_i(v, __builtin_amdgcn_update_dpp(0, v, 0x111, 0xF, 0xF, true)); // row_shr:1
    v = fadd_i(v, __builtin_amdgcn_update_dpp(0, v, 0x112, 0xF, 0xF, true)); // row_shr:2
    v = fadd_i(v, __builtin_amdgcn_update_dpp(0, v, 0x114, 0xF, 0xF, true)); // row_shr:4
    v = fadd_i(v, __builtin_amdgcn_update_dpp(0, v, 0x118, 0xF, 0xF, true)); // row_shr:8
    v = fadd_i(v, __builtin_amdgcn_update_dpp(0, v, 0x142, 0xA, 0xF, true)); // row_bcast:15
    v = fadd_i(v, __builtin_amdgcn_update_dpp(0, v, 0x143, 0xC, 0xF, true)); // row_bcast:31
    return __builtin_bit_cast(float, v);
}

// broadcast lane l's value to all lanes (lands in SGPR)
__device__ __forceinline__ float rl(float x, int l) {
    return __builtin_bit_cast(float, __builtin_amdgcn_readlane(__builtin_bit_cast(int, x), l));
}

// gfx950 register-only row exchanges: with both operands = x, the swap+add
// yields pairwise row sums at every lane position.
__device__ __forceinline__ float rowpair16_sum(float x) {
    float a = x, b = x;
    asm("v_permlane16_swap_b32 %0, %1" : "+v"(a), "+v"(b));
    return a + b;
}
__device__ __forceinline__ float rowpair32_sum(float x) {
    float a = x, b = x;
    asm("v_permlane32_swap_b32 %0, %1" : "+v"(a), "+v"(b));
    return a + b;
}
// sum over the 16 lanes {j, j+4, ..., j+60}: after two row-pair sums every
// lane p holds the all-row sum at its position; shr:4 + shr:8 accumulate the
// stride-4 class so lanes with (l&15)==12+j hold the class-j total (all rows).
__device__ __forceinline__ float cls4_sum(float x) {
    float s = rowpair32_sum(rowpair16_sum(x));
    int v = __builtin_bit_cast(int, s);
    v = fadd_i(v, __builtin_amdgcn_update_dpp(0, v, 0x114, 0xF, 0xF, true)); // row_shr:4
    v = fadd_i(v, __builtin_amdgcn_update_dpp(0, v, 0x118, 0xF, 0xF, true)); // row_shr:8
    return __builtin_bit_cast(float, v);
}

// broadcast element I of each quad to the whole quad (register-only)
template <int I>
__device__ __forceinline__ float quad_bcast(float x) {
    return __builtin_bit_cast(float,
        __builtin_amdgcn_update_dpp(0, __builtin_bit_cast(int, x), I * 0x55, 0xF, 0xF, true));
}

// lgkmcnt-only barrier: ds_writes must be LDS-visible, but do NOT drain vmcnt
// (the per-step `out` global store would otherwise stall every wave here).
__device__ __forceinline__ void barrier_lgkm() {
    asm volatile("s_waitcnt lgkmcnt(0)" ::: "memory");
    __builtin_amdgcn_s_barrier();
    asm volatile("" ::: "memory");
}

__global__ __launch_bounds__(256, 1)
void exphydro_kernel(const float* __restrict__ g_snow, const float* __restrict__ g_water,
                     const float* __restrict__ g_pr, const float* __restrict__ g_tm,
                     const float* __restrict__ g_ld, const float* __restrict__ g_t,
                     const float* __restrict__ W1, const float* __restrict__ b1,
                     const float* __restrict__ W2, const float* __restrict__ b2,
                     const float* __restrict__ W3, const float* __restrict__ b3,
                     const float* __restrict__ W4, const float* __restrict__ b4,
                     float* __restrict__ out, int T)
{
    const int tid  = threadIdx.x;
    const int lane = tid & 63;
    const int wid  = tid >> 6;      // wave id 0..3, one SIMD each
    const int b    = blockIdx.x;    // one sample per block
    const int q4   = lane >> 2;     // quad index 0..15 (owns h1 rows 4q..4q+3)
    const int j4   = lane & 3;      // col class within the wave's 16-col slice

    // forcing interleaved {pr, tm, ld, t} per timestep -- broadcast b128 reads
    __shared__ __align__(16) float4v s_f[TMAX];
    // L3 partial exchange, double-buffered across consecutive rhs calls
    __shared__ __align__(16) float partAB[2][4][64];

    for (int i = tid; i < T; i += 256) {
        s_f[i] = float4v{g_pr[b * T + i], g_tm[b * T + i], g_ld[b * T + i], g_t[i]};
    }

    // --- weights ---
    // layer 1: all waves identical (per-lane column)
    float w1r[4];
#pragma unroll
    for (int j = 0; j < 4; ++j) w1r[j] = W1[j * 64 + lane];
    float b1v = b1[lane];
    // layer 2, quad-task layout: lane (q4,j4) holds W2 rows [4q4..4q4+4) for
    // cols {16*wid + 4m + j4 : m=0..3}; bias per (m) for the col this lane's
    // class reduces to (added post-reduction at lanes (l&15)==12+j, where
    // (12+j)&3 == j makes the per-lane load line up).
    float w2q[4][4], b2q[4];
#pragma unroll
    for (int m = 0; m < 4; ++m) {
#pragma unroll
        for (int i = 0; i < 4; ++i)
            w2q[m][i] = W2[(4 * q4 + i) * 64 + 16 * wid + 4 * m + j4];
        b2q[m] = b2[16 * wid + 4 * m + j4];
    }
    // layer 3, K-split: wave owns rows [16*wid, 16*wid+16), lane = output col.
    float w3f[16];
#pragma unroll
    for (int k = 0; k < 16; ++k) w3f[k] = W3[(16 * wid + k) * 64 + lane];
    float b3v = (wid == 0) ? b3[lane] : 0.0f;
    // layer 4: full, redundant per wave
    float w4r[5], b4r[5];
#pragma unroll
    for (int k = 0; k < 5; ++k) { w4r[k] = W4[lane * 5 + k]; b4r[k] = b4[k]; }

    __syncthreads();

    // full MLP from per-lane h1; o[0..4] VALID IN LANE 63 of every wave.
    // L2 is register-only (no LDS); ONE lgkm-only barrier per call (L3 exchange).
    auto mlp_o63 = [&](float h1, float (*part)[64], float* o) {
        // quad-gather h1 (register-only DPP broadcasts)
        float h10 = quad_bcast<0>(h1), h11 = quad_bcast<1>(h1),
              h12 = quad_bcast<2>(h1), h13 = quad_bcast<3>(h1);
        // 4x4 partials: reg m = cols 16*wid + 4m + j4, rows 4q4..4q4+3
        float t0 = fmaf(w2q[0][3], h13, fmaf(w2q[0][2], h12, fmaf(w2q[0][1], h11, w2q[0][0] * h10)));
        float t1 = fmaf(w2q[1][3], h13, fmaf(w2q[1][2], h12, fmaf(w2q[1][1], h11, w2q[1][0] * h10)));
        float t2 = fmaf(w2q[2][3], h13, fmaf(w2q[2][2], h12, fmaf(w2q[2][1], h11, w2q[2][0] * h10)));
        float t3 = fmaf(w2q[3][3], h13, fmaf(w2q[3][2], h12, fmaf(w2q[3][1], h11, w2q[3][0] * h10)));
        // class reduction: lanes (l&15)==12+j hold col (4m+j) totals
        t0 = cls4_sum(t0); t1 = cls4_sum(t1); t2 = cls4_sum(t2); t3 = cls4_sum(t3);
        float g0 = ftanh(t0 + b2q[0]);
        float g1 = ftanh(t1 + b2q[1]);
        float g2 = ftanh(t2 + b2q[2]);
        float g3 = ftanh(t3 + b2q[3]);
        // L3: h2[k] (k = 4m+j) = lane 12+j of g_m -> 16 readlane + fmac
        float c0 = b3v, c1 = 0.0f, c2 = 0.0f, c3 = 0.0f;
        c0 = fmaf(w3f[ 0], rl(g0, 12), c0);
        c1 = fmaf(w3f[ 1], rl(g0, 13), c1);
        c2 = fmaf(w3f[ 2], rl(g0, 14), c2);
        c3 = fmaf(w3f[ 3], rl(g0, 15), c3);
        c0 = fmaf(w3f[ 4], rl(g1, 12), c0);
        c1 = fmaf(w3f[ 5], rl(g1, 13), c1);
        c2 = fmaf(w3f[ 6], rl(g1, 14), c2);
        c3 = fmaf(w3f[ 7], rl(g1, 15), c3);
        c0 = fmaf(w3f[ 8], rl(g2, 12), c0);
        c1 = fmaf(w3f[ 9], rl(g2, 13), c1);
        c2 = fmaf(w3f[10], rl(g2, 14), c2);
        c3 = fmaf(w3f[11], rl(g2, 15), c3);
        c0 = fmaf(w3f[12], rl(g3, 12), c0);
        c1 = fmaf(w3f[13], rl(g3, 13), c1);
        c2 = fmaf(w3f[14], rl(g3, 14), c2);
        c3 = fmaf(w3f[15], rl(g3, 15), c3);
        part[wid][lane] = (c0 + c1) + (c2 + c3);
        barrier_lgkm();                              // the ONE barrier (lgkm-only)
        float h3 = ftanh((part[0][lane] + part[1][lane]) + (part[2][lane] + part[3][lane]));
        // L4: 5 DPP trees, redundant in every wave (no LDS, no barrier)
#pragma unroll
        for (int k = 0; k < 5; ++k) o[k] = wave_sum63(w4r[k] * h3) + b4r[k];
    };

    // rhs: d0,d1 wave-uniform via readlane(63); o4 valid in lane 63 only.
    auto rhs = [&](float base, float y0v, float y1v, float ld, float snt,
                   float (*part)[64], float& d0, float& d1, float& o4) {
        // state-only nonlinearities first: overlap with the matvecs
        float step0 = fstep(y0v);
        float st1   = fstep(y1v);
        float h1 = ftanh(fmaf(w1r[0], y0v, fmaf(w1r[1], y1v, base)));
        float o[5];
        mlp_o63(h1, part, o);
        // epilogue computed with lane-63 values (garbage in other lanes, unused)
        float psnow = fmaxf(0.0f, fsinh(o[0]) * snt);
        float prain = fmaxf(0.0f, fsinh(o[1]));
        float melt  = fmaxf(0.0f, step0 * fsinh(o[2]));
        float eq    = st1 * fmaf(fexp(o[3]), ld, fexp(o[4]));
        float d0l = psnow - melt;
        float d1l = (prain + melt) - eq;
        d0 = rl(d0l, 63);
        d1 = rl(d1l, 63);
        o4 = o[4];
    };

    // wave-uniform state, replicated per wave (identical arithmetic => identical)
    float y0v = g_snow[b * T];
    float y1v = g_water[b * T];

    for (int st = 0; st < T - 1; ++st) {
        float4v fc = s_f[st];
        float4v fn = s_f[st + 1];

        float dt = fn.w - fc.w, half = 0.5f * dt, c6 = dt * (1.0f / 6.0f);
        float prH = 0.5f * (fc.x + fn.x);
        float tmH = 0.5f * (fc.y + fn.y);
        float ldH = 0.5f * (fc.z + fn.z);
        float snA = fstep(-fc.y), snH = fstep(-tmH), snC = fstep(-fn.y);
        float baseA = fmaf(w1r[2], fc.x, fmaf(w1r[3], fc.y, b1v));
        float baseH = fmaf(w1r[2], prH,  fmaf(w1r[3], tmH,  b1v));
        float baseC = fmaf(w1r[2], fn.x, fmaf(w1r[3], fn.y, b1v));

        float k1a, k1b, k2a, k2b, k3a, k3b, k4a, k4b, o4a, o4x;
        rhs(baseA, y0v, y1v, fc.z, snA, partAB[0], k1a, k1b, o4a);
        // q_out[:, st] == o[4] of the k1 MLP eval (integer-time interp == raw series)
        if (tid == 63) out[b * T + st] = o4a;
        rhs(baseH, fmaf(half, k1a, y0v), fmaf(half, k1b, y1v), ldH, snH, partAB[1], k2a, k2b, o4x);
        rhs(baseH, fmaf(half, k2a, y0v), fmaf(half, k2b, y1v), ldH, snH, partAB[0], k3a, k3b, o4x);
        rhs(baseC, fmaf(dt, k3a, y0v),   fmaf(dt, k3b, y1v),   fn.z, snC, partAB[1], k4a, k4b, o4x);

        y0v = fmaf(c6, (k1a + k4a) + 2.0f * (k2a + k3a), y0v);
        y1v = fmaf(c6, (k1b + k4b) + 2.0f * (k2b + k3b), y1v);
    }

    // last readout at t = T-1 with raw series values and final state
    {
        float4v fL = s_f[T - 1];
        float base = fmaf(w1r[2], fL.x, fmaf(w1r[3], fL.y, b1v));
        float h1 = ftanh(fmaf(w1r[0], y0v, fmaf(w1r[1], y1v, base)));
        float o[5];
        mlp_o63(h1, partAB[0], o);
        if (tid == 63) out[b * T + (T - 1)] = o[4];
    }
}

extern "C" void kernel_launch(void* const* d_in, const int* in_sizes, int n_in,
                              void* d_out, int out_size, void* d_ws, size_t ws_size,
                              hipStream_t stream) {
    const float* g_snow  = (const float*)d_in[0];
    const float* g_water = (const float*)d_in[1];
    const float* g_pr    = (const float*)d_in[2];
    const float* g_tm    = (const float*)d_in[3];
    const float* g_ld    = (const float*)d_in[4];
    const float* g_t     = (const float*)d_in[5];
    const float* W1 = (const float*)d_in[6];
    const float* b1 = (const float*)d_in[7];
    const float* W2 = (const float*)d_in[8];
    const float* b2 = (const float*)d_in[9];
    const float* W3 = (const float*)d_in[10];
    const float* b3 = (const float*)d_in[11];
    const float* W4 = (const float*)d_in[12];
    const float* b4 = (const float*)d_in[13];

    const int T = in_sizes[5];
    const int B = in_sizes[0] / T;

    exphydro_kernel<<<dim3(B), dim3(256), 0, stream>>>(
        g_snow, g_water, g_pr, g_tm, g_ld, g_t,
        W1, b1, W2, b2, W3, b3, W4, b4,
        (float*)d_out, T);
}